// Round 1
// baseline (487.789 us; speedup 1.0000x reference)
//
#include <hip/hip_runtime.h>
#include <stdint.h>

typedef __attribute__((ext_vector_type(8))) short short8;
typedef __attribute__((ext_vector_type(4))) short sh4;
typedef __attribute__((ext_vector_type(4))) float floatx4;
typedef __attribute__((ext_vector_type(4))) unsigned int uintx4;

__device__ __forceinline__ float bs2f(short s) {
  union { unsigned int u; float f; } cv;
  cv.u = ((unsigned int)(unsigned short)s) << 16;
  return cv.f;
}
__device__ __forceinline__ short f2bs(float x) {
  union { float f; unsigned int u; } cv; cv.f = x;
  unsigned int u = cv.u;
  u += 0x7fffu + ((u >> 16) & 1u);   // round-to-nearest-even
  return (short)(u >> 16);
}
// pack two fp32 -> bf16x2 (round-half-up) in 3 VALU: two adds + v_perm
__device__ __forceinline__ unsigned int pack_bf16(float a, float b) {
  unsigned int ua = __float_as_uint(a) + 0x8000u;
  unsigned int ub = __float_as_uint(b) + 0x8000u;
  return __builtin_amdgcn_perm(ub, ua, 0x07060302u);  // [ub.hi16 : ua.hi16]
}
// async global->LDS, 16 bytes per lane (wave-uniform LDS base + lane*16)
__device__ __forceinline__ void async_copy16(const void* g, void* l) {
  __builtin_amdgcn_global_load_lds(
      (const __attribute__((address_space(1))) void*)g,
      (__attribute__((address_space(3))) void*)l, 16, 0, 0);
}

#define BM 128
#define BN 128
#define BK 64

// T1: XCD-aware bijective swizzle for an 8 x 128 grid slice (1024 blocks,
// 8 XCDs, 1024 % 8 == 0 so bijective). Consecutive linear ids round-robin
// XCDs; remap so each XCD owns 16 contiguous m-strips and each strip's 8
// n-blocks (which share the A row-panel) run on ONE XCD -> A reuse in L2.
__device__ __forceinline__ void swizzle_mn(int& m0, int& n0) {
  int flat = blockIdx.x + (blockIdx.y << 3);   // gridDim.x == 8
  int swz = (flat & 7) * 128 + (flat >> 3);    // gridDim.y == 128
  n0 = (swz & 7) * BN;
  m0 = (swz >> 3) * BM;
}

// ---------------------------------------------------------------------------
// Fused projection GEMMs: C = bf16(A_fp32) @ B^T, two problems selected by
// blockIdx.z. Double-buffered LDS + T14 async-STAGE split:
//   per K-step: issue async B -> buf^1, issue fp32 A loads -> regs (early),
//   compute buf, pack+ds_write A -> buf^1 (late), ONE barrier, swap.
// ---------------------------------------------------------------------------
__global__ __launch_bounds__(256) void gemm_proj(
    const float* __restrict__ A0, const short* __restrict__ B0,
    short* __restrict__ C0,
    const float* __restrict__ A1, const short* __restrict__ B1,
    short* __restrict__ C1, int N, int K)
{
  __shared__ __align__(16) short As[2][BM * BK];
  __shared__ __align__(16) short Bs[2][BN * BK];
  const float* Ap = blockIdx.z ? A1 : A0;
  const short* Bp = blockIdx.z ? B1 : B0;
  short*       Cp = blockIdx.z ? C1 : C0;

  const int tid  = threadIdx.x;
  const int wave = tid >> 6;
  const int lane = tid & 63;
  const int lm = lane & 15, lq = lane >> 4;
  int m0, n0;
  swizzle_mn(m0, n0);
  const int wm = (wave & 1) * 64, wn = (wave >> 1) * 64;
  const int r8 = tid >> 3, cc = (tid & 7) * 8;   // staging coords

  floatx4 acc[4][4];
#pragma unroll
  for (int r = 0; r < 4; ++r)
#pragma unroll
    for (int c = 0; c < 4; ++c) acc[r][c] = (floatx4)0.0f;

  floatx4 pa[4][2];   // prefetched fp32 A (static indexing only)

  // ---- prologue: tile 0 -> buffer 0
#pragma unroll
  for (int it = 0; it < 4; ++it) {
    int r = it * 32 + r8;
    async_copy16(&Bp[(size_t)(n0 + r) * K + cc], &Bs[0][r * BK + cc]);
  }
#pragma unroll
  for (int it = 0; it < 4; ++it) {
    const float* ap = Ap + (size_t)(m0 + it * 32 + r8) * K + cc;
    pa[it][0] = *reinterpret_cast<const floatx4*>(ap);
    pa[it][1] = *reinterpret_cast<const floatx4*>(ap + 4);
  }
#pragma unroll
  for (int it = 0; it < 4; ++it) {
    uintx4 av;
    av[0] = pack_bf16(pa[it][0][0], pa[it][0][1]);
    av[1] = pack_bf16(pa[it][0][2], pa[it][0][3]);
    av[2] = pack_bf16(pa[it][1][0], pa[it][1][1]);
    av[3] = pack_bf16(pa[it][1][2], pa[it][1][3]);
    *reinterpret_cast<uintx4*>(&As[0][(it * 32 + r8) * BK + cc]) = av;
  }
  __syncthreads();

  const int nt = K / BK;
  int cur = 0;
  for (int t = 0; t < nt - 1; ++t) {
    const int nxt = cur ^ 1;
    const int kb = (t + 1) * BK;
    // issue-early: next B tile async into buf^1
#pragma unroll
    for (int it = 0; it < 4; ++it) {
      int r = it * 32 + r8;
      async_copy16(&Bp[(size_t)(n0 + r) * K + kb + cc], &Bs[nxt][r * BK + cc]);
    }
    // issue-early: next fp32 A tile into registers
#pragma unroll
    for (int it = 0; it < 4; ++it) {
      const float* ap = Ap + (size_t)(m0 + it * 32 + r8) * K + kb + cc;
      pa[it][0] = *reinterpret_cast<const floatx4*>(ap);
      pa[it][1] = *reinterpret_cast<const floatx4*>(ap + 4);
    }
    // compute current tile (loads fly under the MFMAs)
#pragma unroll
    for (int kk = 0; kk < BK; kk += 32) {
      short8 af[4], bfr[4];
#pragma unroll
      for (int r = 0; r < 4; ++r)
        af[r] = *reinterpret_cast<const short8*>(
            &As[cur][(wm + r * 16 + lm) * BK + kk + lq * 8]);
#pragma unroll
      for (int c = 0; c < 4; ++c)
        bfr[c] = *reinterpret_cast<const short8*>(
            &Bs[cur][(wn + c * 16 + lm) * BK + kk + lq * 8]);
#pragma unroll
      for (int r = 0; r < 4; ++r)
#pragma unroll
        for (int c = 0; c < 4; ++c)
          acc[r][c] = __builtin_amdgcn_mfma_f32_16x16x32_bf16(
              af[r], bfr[c], acc[r][c], 0, 0, 0);
    }
    // write-late: pack prefetched A into buf^1
#pragma unroll
    for (int it = 0; it < 4; ++it) {
      uintx4 av;
      av[0] = pack_bf16(pa[it][0][0], pa[it][0][1]);
      av[1] = pack_bf16(pa[it][0][2], pa[it][0][3]);
      av[2] = pack_bf16(pa[it][1][0], pa[it][1][1]);
      av[3] = pack_bf16(pa[it][1][2], pa[it][1][3]);
      *reinterpret_cast<uintx4*>(&As[nxt][(it * 32 + r8) * BK + cc]) = av;
    }
    __syncthreads();   // drains vmcnt: B(t+1) landed; all waves done with cur
    cur = nxt;
  }
  // final tile
#pragma unroll
  for (int kk = 0; kk < BK; kk += 32) {
    short8 af[4], bfr[4];
#pragma unroll
    for (int r = 0; r < 4; ++r)
      af[r] = *reinterpret_cast<const short8*>(
          &As[cur][(wm + r * 16 + lm) * BK + kk + lq * 8]);
#pragma unroll
    for (int c = 0; c < 4; ++c)
      bfr[c] = *reinterpret_cast<const short8*>(
          &Bs[cur][(wn + c * 16 + lm) * BK + kk + lq * 8]);
#pragma unroll
    for (int r = 0; r < 4; ++r)
#pragma unroll
      for (int c = 0; c < 4; ++c)
        acc[r][c] = __builtin_amdgcn_mfma_f32_16x16x32_bf16(
            af[r], bfr[c], acc[r][c], 0, 0, 0);
  }

#pragma unroll
  for (int r = 0; r < 4; ++r)
#pragma unroll
    for (int c = 0; c < 4; ++c) {
      int col = n0 + wn + c * 16 + lm;
#pragma unroll
      for (int reg = 0; reg < 4; ++reg) {
        int row = m0 + wm + r * 16 + lq * 4 + reg;  // C/D: col=lane&15, row=quad*4+reg
        Cp[(size_t)row * N + col] = f2bs(acc[r][c][reg]);
      }
    }
}

// ---------------------------------------------------------------------------
// Out-projection GEMM: bf16 A via global_load_lds (proven m97 structure,
// single-buffer, 32 KB LDS, high co-resident-block overlap) + T1 swizzle.
// ---------------------------------------------------------------------------
template<int RESID, int OUTF32>
__global__ __launch_bounds__(256) void gemm_bt(
    const short* __restrict__ A, const short* __restrict__ BT,
    void* __restrict__ Cv, const short* __restrict__ resid,
    int M, int N, int K)
{
  __shared__ __align__(16) short As[BM * BK];
  __shared__ __align__(16) short Bs[BN * BK];
  const int tid  = threadIdx.x;
  const int wave = tid >> 6;
  const int lane = tid & 63;
  const int lm   = lane & 15;
  const int lq   = lane >> 4;
  int m0, n0;
  swizzle_mn(m0, n0);
  const int wm = (wave & 1) * 64;
  const int wn = (wave >> 1) * 64;

  floatx4 acc[4][4];
#pragma unroll
  for (int r = 0; r < 4; ++r)
#pragma unroll
    for (int c = 0; c < 4; ++c) acc[r][c] = (floatx4)0.0f;

  for (int k0 = 0; k0 < K; k0 += BK) {
    __syncthreads();
#pragma unroll
    for (int it = 0; it < 4; ++it) {
      int chunk = it * 256 + tid;
      int r = chunk >> 3, cc = (chunk & 7) * 8;
      async_copy16(&BT[(size_t)(n0 + r) * K + k0 + cc], &Bs[r * BK + cc]);
    }
#pragma unroll
    for (int it = 0; it < 4; ++it) {
      int chunk = it * 256 + tid;
      int r = chunk >> 3, cc = (chunk & 7) * 8;
      async_copy16(&A[(size_t)(m0 + r) * K + k0 + cc], &As[r * BK + cc]);
    }
    __syncthreads();
#pragma unroll
    for (int kk = 0; kk < BK; kk += 32) {
      short8 af[4], bfr[4];
#pragma unroll
      for (int r = 0; r < 4; ++r)
        af[r] = *reinterpret_cast<const short8*>(&As[(wm + r * 16 + lm) * BK + kk + lq * 8]);
#pragma unroll
      for (int c = 0; c < 4; ++c)
        bfr[c] = *reinterpret_cast<const short8*>(&Bs[(wn + c * 16 + lm) * BK + kk + lq * 8]);
#pragma unroll
      for (int r = 0; r < 4; ++r)
#pragma unroll
        for (int c = 0; c < 4; ++c)
          acc[r][c] = __builtin_amdgcn_mfma_f32_16x16x32_bf16(af[r], bfr[c], acc[r][c], 0, 0, 0);
    }
  }

#pragma unroll
  for (int r = 0; r < 4; ++r)
#pragma unroll
    for (int c = 0; c < 4; ++c) {
      int col = n0 + wn + c * 16 + lm;
#pragma unroll
      for (int reg = 0; reg < 4; ++reg) {
        int row = m0 + wm + r * 16 + lq * 4 + reg;   // C/D: col=lane&15, row=quad*4+reg
        size_t idx = (size_t)row * N + col;
        float v = acc[r][c][reg];
        if (RESID) v += bs2f(resid[idx]);
        if (OUTF32) ((float*)Cv)[idx] = v;
        else        ((short*)Cv)[idx] = f2bs(v);
      }
    }
}

// out[n][k] = bf16(in[k][n]) for 1024x1024 fp32; blockIdx.z selects matrix
__global__ __launch_bounds__(256) void transpose_cvt3(
    const float* __restrict__ i0, const float* __restrict__ i1,
    const float* __restrict__ i2, short* __restrict__ o0,
    short* __restrict__ o1, short* __restrict__ o2) {
  const float* in = blockIdx.z == 0 ? i0 : (blockIdx.z == 1 ? i1 : i2);
  short* out = blockIdx.z == 0 ? o0 : (blockIdx.z == 1 ? o1 : o2);
  __shared__ short tile[32][33];
  int bx = blockIdx.x * 32, by = blockIdx.y * 32;
  int tx = threadIdx.x & 31;
  int ty = threadIdx.x >> 5;
#pragma unroll
  for (int i = 0; i < 32; i += 8)
    tile[ty + i][tx] = f2bs(in[(size_t)(by + ty + i) * 1024 + bx + tx]);
  __syncthreads();
#pragma unroll
  for (int i = 0; i < 32; i += 8)
    out[(size_t)(bx + ty + i) * 1024 + by + tx] = tile[tx][ty + i];
}

// WaB[e][k] = bf16(Wa[k][e]), same for Wb. grid 128 x 256.
__global__ __launch_bounds__(256) void w_transpose(const float* __restrict__ Wa,
                                                   const float* __restrict__ Wb,
                                                   short* __restrict__ WaB,
                                                   short* __restrict__ WbB) {
  int idx = blockIdx.x * 256 + threadIdx.x;   // 0..32767
  const float* src = idx < 16384 ? Wa : Wb;
  short* dst = idx < 16384 ? WaB : WbB;
  int i = idx & 16383;
  int e = i >> 10, k = i & 1023;
  dst[i] = f2bs(src[k * 16 + e]);
}

// Skinny MFMA GEMM: out[(b*16+e)*2048 + s] = 0.125 * sum_k A[row,k] * W[k,e]
// SCRAMBLE=0: A row = blk*16+m directly from X (Qb).
// SCRAMBLE=1: row sp=h*128+t reads X=Kb[b, t*16+u, h*64+j] * qg[b,h*64+j]
//             (the Fastformer reshape scramble; j-chunks stay contiguous).
// WB is W^T as bf16 [16][1024]. One wave per 16-row strip; grid 1024.
template<int SCRAMBLE>
__global__ __launch_bounds__(64) void skinny_logits(
    const short* __restrict__ X, const short* __restrict__ WB,
    const float* __restrict__ qg, float* __restrict__ out)
{
  const int lane = threadIdx.x;
  const int lm = lane & 15, lq = lane >> 4;
  const int blk = blockIdx.x;           // 0..1023
  const int b = blk >> 7;
  const int s0 = (blk & 127) * 16;      // row offset within batch
  floatx4 acc = (floatx4)0.0f;
  const short* b0 = WB + lm * 1024 + lq * 8;

  if (!SCRAMBLE) {
    const short* a0 = X + ((size_t)(b * 2048 + s0 + lm)) * 1024 + lq * 8;
#pragma unroll 16
    for (int c = 0; c < 32; ++c) {
      short8 a  = *reinterpret_cast<const short8*>(a0 + c * 32);
      short8 bf = *reinterpret_cast<const short8*>(b0 + c * 32);
      acc = __builtin_amdgcn_mfma_f32_16x16x32_bf16(a, bf, acc, 0, 0, 0);
    }
  } else {
    const int h = s0 >> 7, t0 = s0 & 127;
    const float* qgp = qg + b * 1024 + h * 64;
    const short* xb = X + ((size_t)(b * 2048 + (t0 + lm) * 16)) * 1024 + h * 64;
#pragma unroll 16
    for (int c = 0; c < 32; ++c) {
      int dp = c * 32 + lq * 8;         // k index within 1024
      int u = dp >> 6, j0 = dp & 63;    // 8-aligned, never crosses u
      short8 a = *reinterpret_cast<const short8*>(xb + (size_t)u * 1024 + j0);
      floatx4 g0 = *reinterpret_cast<const floatx4*>(qgp + j0);
      floatx4 g1 = *reinterpret_cast<const floatx4*>(qgp + j0 + 4);
      uintx4 av;
      av[0] = pack_bf16(bs2f(a[0]) * g0[0], bs2f(a[1]) * g0[1]);
      av[1] = pack_bf16(bs2f(a[2]) * g0[2], bs2f(a[3]) * g0[3]);
      av[2] = pack_bf16(bs2f(a[4]) * g1[0], bs2f(a[5]) * g1[1]);
      av[3] = pack_bf16(bs2f(a[6]) * g1[2], bs2f(a[7]) * g1[3]);
      short8 as = __builtin_bit_cast(short8, av);
      short8 bf = *reinterpret_cast<const short8*>(b0 + c * 32);
      acc = __builtin_amdgcn_mfma_f32_16x16x32_bf16(as, bf, acc, 0, 0, 0);
    }
  }
  // D: col(e)=lane&15, row=lq*4+reg; rows are consecutive s -> float4 store
  float* o = out + ((size_t)(b * 16 + lm)) * 2048 + s0 + lq * 4;
  floatx4 r;
#pragma unroll
  for (int i = 0; i < 4; ++i) r[i] = acc[i] * 0.125f;
  *reinterpret_cast<floatx4*>(o) = r;
}

// in-place softmax over each 2048-row; grid = 128 (b,h) rows
__global__ __launch_bounds__(256) void softmax_rows(float* __restrict__ logits) {
  __shared__ float red[256];
  int tid = threadIdx.x;
  float* l = logits + (size_t)blockIdx.x * 2048;
  float v[8];
  float lm = -3.0e38f;
#pragma unroll
  for (int i = 0; i < 8; ++i) { v[i] = l[tid + i * 256]; lm = fmaxf(lm, v[i]); }
  red[tid] = lm; __syncthreads();
  for (int s2 = 128; s2 > 0; s2 >>= 1) {
    if (tid < s2) red[tid] = fmaxf(red[tid], red[tid + s2]);
    __syncthreads();
  }
  float m = red[0];
  __syncthreads();
  float ls = 0.f;
#pragma unroll
  for (int i = 0; i < 8; ++i) { v[i] = __expf(v[i] - m); ls += v[i]; }
  red[tid] = ls; __syncthreads();
  for (int s2 = 128; s2 > 0; s2 >>= 1) {
    if (tid < s2) red[tid] += red[tid + s2];
    __syncthreads();
  }
  float inv = 1.0f / red[0];
#pragma unroll
  for (int i = 0; i < 8; ++i) l[tid + i * 256] = v[i] * inv;
}

// partial weighted pooling: grid 512 (b=blk>>6, sc=blk&63), 32 s-rows each.
// part[blk][d] = sum_{s in chunk} probs[b, d>>6, s] * X[b,s,d]  (coalesced 8B/lane)
__global__ __launch_bounds__(256) void pool_partial(const float* __restrict__ probs,
                                                    const short* __restrict__ X,
                                                    float* __restrict__ part) {
  __shared__ float p[16][32];
  int blk = blockIdx.x, b = blk >> 6, sc = blk & 63, s0 = sc * 32;
  int tid = threadIdx.x;
  {
    int h = tid >> 4, ss = (tid & 15) * 2;
    const float* pr = probs + (size_t)(b * 16 + h) * 2048 + s0 + ss;
    p[h][ss] = pr[0]; p[h][ss + 1] = pr[1];
  }
  __syncthreads();
  int d = tid * 4, h = tid >> 4;
  float a0 = 0, a1 = 0, a2 = 0, a3 = 0;
  const short* Xp = X + ((size_t)b * 2048 + s0) * 1024 + d;
#pragma unroll 4
  for (int s = 0; s < 32; ++s) {
    sh4 x = *reinterpret_cast<const sh4*>(Xp + (size_t)s * 1024);
    float w = p[h][s];
    a0 += w * bs2f(x[0]); a1 += w * bs2f(x[1]);
    a2 += w * bs2f(x[2]); a3 += w * bs2f(x[3]);
  }
  float* o = part + (size_t)blk * 1024 + d;
  o[0] = a0; o[1] = a1; o[2] = a2; o[3] = a3;
}

// out[b*1024+d] = (SCALE ? g[b*1024+d] : 1) * sum_{sc<64} part[(b*64+sc)*1024+d]
template<int SCALE>
__global__ __launch_bounds__(256) void pool_reduce(const float* __restrict__ part,
                                                   const float* __restrict__ g,
                                                   float* __restrict__ out) {
  int b = blockIdx.x, d = threadIdx.x * 4;
  float a0 = 0, a1 = 0, a2 = 0, a3 = 0;
  for (int sc = 0; sc < 64; ++sc) {
    const float* pp = part + (size_t)(b * 64 + sc) * 1024 + d;
    a0 += pp[0]; a1 += pp[1]; a2 += pp[2]; a3 += pp[3];
  }
  if (SCALE) {
    const float* gp = g + b * 1024 + d;
    a0 *= gp[0]; a1 *= gp[1]; a2 *= gp[2]; a3 *= gp[3];
  }
  float* op = out + b * 1024 + d;
  op[0] = a0; op[1] = a1; op[2] = a2; op[3] = a3;
}

// QG[b,s,d] = bf16( Qb[b,s,d] * g[b*1024+d] )
__global__ __launch_bounds__(256) void scale_a(const short* __restrict__ Qb,
                                               const float* __restrict__ g,
                                               short* __restrict__ QG) {
  size_t base = ((size_t)blockIdx.x * 256 + threadIdx.x) * 8;
  int b = (int)(base >> 21), d = (int)(base & 1023);
  short8 v = *reinterpret_cast<const short8*>(&Qb[base]);
  const float* gp = g + b * 1024 + d;
#pragma unroll
  for (int e = 0; e < 8; ++e) v[e] = f2bs(bs2f(v[e]) * gp[e]);
  *reinterpret_cast<short8*>(&QG[base]) = v;
}

extern "C" void kernel_launch(void* const* d_in, const int* in_sizes, int n_in,
                              void* d_out, int out_size, void* d_ws, size_t ws_size,
                              hipStream_t stream) {
  (void)in_sizes; (void)n_in; (void)out_size; (void)ws_size;
  const float* Qseq = (const float*)d_in[0];
  const float* Kseq = (const float*)d_in[1];
  // d_in[2] = V_seq, unused (faithful to reference)
  const float* WQ = (const float*)d_in[3];
  const float* WK = (const float*)d_in[4];
  const float* Wa = (const float*)d_in[5];
  const float* Wb = (const float*)d_in[6];
  const float* WP = (const float*)d_in[7];
  float* outp = (float*)d_out;

  char* ws = (char*)d_ws;
  const size_t MB = 1024 * 1024;
  short* Qb   = (short*)(ws + 0);           // 32 MB bf16 Q
  short* Kb   = (short*)(ws + 32 * MB);     // 32 MB bf16 K; reused for QG after pool2
  short* WQT  = (short*)(ws + 64 * MB);     // 2 MB
  short* WKT  = (short*)(ws + 66 * MB);     // 2 MB
  short* WPT  = (short*)(ws + 68 * MB);     // 2 MB
  float* la   = (float*)(ws + 70 * MB);     // 1 MB
  float* lb   = (float*)(ws + 71 * MB);     // 1 MB
  float* qg   = (float*)(ws + 72 * MB);     // 32 KB
  float* gv   = (float*)(ws + 72 * MB + 64 * 1024); // 32 KB
  short* WaB  = (short*)(ws + 72 * MB + 128 * 1024); // 32 KB bf16 Wa^T
  short* WbB  = (short*)(ws + 72 * MB + 192 * 1024); // 32 KB bf16 Wb^T
  float* part = (float*)(ws + 73 * MB);     // 2 MB
  short* QG   = Kb;                         // Kb dead after pool2

  dim3 tb(256);
  transpose_cvt3<<<dim3(32, 32, 3), tb, 0, stream>>>(WQ, WK, WP, WQT, WKT, WPT);
  w_transpose<<<128, tb, 0, stream>>>(Wa, Wb, WaB, WbB);

  // fused Q/K projections (z selects problem), dbuf + T14 + XCD swizzle
  gemm_proj<<<dim3(8, 128, 2), tb, 0, stream>>>(
      Qseq, WQT, Qb, Kseq, WKT, Kb, 1024, 1024);

  skinny_logits<0><<<1024, 64, 0, stream>>>(Qb, WaB, nullptr, la);
  softmax_rows<<<128, tb, 0, stream>>>(la);
  pool_partial<<<512, tb, 0, stream>>>(la, Qb, part);
  pool_reduce<0><<<8, tb, 0, stream>>>(part, nullptr, qg);

  skinny_logits<1><<<1024, 64, 0, stream>>>(Kb, WbB, qg, lb);
  softmax_rows<<<128, tb, 0, stream>>>(lb);
  pool_partial<<<512, tb, 0, stream>>>(lb, Kb, part);
  pool_reduce<1><<<8, tb, 0, stream>>>(part, qg, gv);

  scale_a<<<8192, tb, 0, stream>>>(Qb, gv, QG);
  gemm_bt<1, 1><<<dim3(8, 128), tb, 0, stream>>>(QG, WPT, outp, Qb, 16384, 1024, 1024);
}

// Round 2
// 441.514 us; speedup vs baseline: 1.1048x; 1.1048x over previous
//
#include <hip/hip_runtime.h>
#include <stdint.h>

typedef __attribute__((ext_vector_type(8))) short short8;
typedef __attribute__((ext_vector_type(4))) short sh4;
typedef __attribute__((ext_vector_type(4))) float floatx4;
typedef __attribute__((ext_vector_type(4))) unsigned int uintx4;

__device__ __forceinline__ float bs2f(short s) {
  union { unsigned int u; float f; } cv;
  cv.u = ((unsigned int)(unsigned short)s) << 16;
  return cv.f;
}
__device__ __forceinline__ short f2bs(float x) {
  union { float f; unsigned int u; } cv; cv.f = x;
  unsigned int u = cv.u;
  u += 0x7fffu + ((u >> 16) & 1u);   // round-to-nearest-even
  return (short)(u >> 16);
}
// pack two fp32 -> bf16x2 (round-half-up) in 3 VALU: two adds + v_perm
__device__ __forceinline__ unsigned int pack_bf16(float a, float b) {
  unsigned int ua = __float_as_uint(a) + 0x8000u;
  unsigned int ub = __float_as_uint(b) + 0x8000u;
  return __builtin_amdgcn_perm(ub, ua, 0x07060302u);  // [ub.hi16 : ua.hi16]
}
// async global->LDS, 16 bytes per lane (wave-uniform LDS base + lane*16)
__device__ __forceinline__ void async_copy16(const void* g, void* l) {
  __builtin_amdgcn_global_load_lds(
      (const __attribute__((address_space(1))) void*)g,
      (__attribute__((address_space(3))) void*)l, 16, 0, 0);
}

#define BM 128
#define BN 128
#define BK 64

// T1: XCD-aware bijective swizzle for an 8 x 128 grid slice (1024 blocks,
// 8 XCDs, 1024 % 8 == 0 so bijective). HW round-robins linear block id over
// XCDs (XCD = blockIdx.x here since gridDim.x == 8); remap so each XCD owns
// 16 contiguous m-strips with all 8 n-blocks of each strip -> the A row-panel
// is fetched by ONE XCD's L2 instead of all eight.
// Measured r1: FETCH 528 MB -> 98 MB for the projection pair.
__device__ __forceinline__ void swizzle_mn(int& m0, int& n0) {
  int flat = blockIdx.x + (blockIdx.y << 3);   // gridDim.x == 8
  int swz = (flat & 7) * 128 + (flat >> 3);    // gridDim.y == 128
  n0 = (swz & 7) * BN;
  m0 = (swz >> 3) * BM;
}

// ---------------------------------------------------------------------------
// Fused projection GEMMs: C = bf16(A_fp32) @ B^T, problem selected by
// blockIdx.z. Single-buffer 32 KB LDS, 2-barrier structure (round-0 proven:
// 91 us/GEMM; r1 showed 64 KB dbuf kills block residency -> m132 regression).
// A staged fp32->reg->pack->ds_write; B async via global_load_lds.
// ---------------------------------------------------------------------------
__global__ __launch_bounds__(256) void gemm_proj(
    const float* __restrict__ A0, const short* __restrict__ B0,
    short* __restrict__ C0,
    const float* __restrict__ A1, const short* __restrict__ B1,
    short* __restrict__ C1, int N, int K)
{
  __shared__ __align__(16) short As[BM * BK];
  __shared__ __align__(16) short Bs[BN * BK];
  const float* Ap = blockIdx.z ? A1 : A0;
  const short* Bp = blockIdx.z ? B1 : B0;
  short*       Cp = blockIdx.z ? C1 : C0;

  const int tid  = threadIdx.x;
  const int wave = tid >> 6;
  const int lane = tid & 63;
  const int lm = lane & 15, lq = lane >> 4;
  int m0, n0;
  swizzle_mn(m0, n0);
  const int wm = (wave & 1) * 64, wn = (wave >> 1) * 64;

  floatx4 acc[4][4];
#pragma unroll
  for (int r = 0; r < 4; ++r)
#pragma unroll
    for (int c = 0; c < 4; ++c) acc[r][c] = (floatx4)0.0f;

  for (int k0 = 0; k0 < K; k0 += BK) {
    __syncthreads();
    // B tile: async direct-to-LDS
#pragma unroll
    for (int it = 0; it < 4; ++it) {
      int chunk = it * 256 + tid;
      int r = chunk >> 3, cc = (chunk & 7) * 8;
      async_copy16(&Bp[(size_t)(n0 + r) * K + k0 + cc], &Bs[r * BK + cc]);
    }
    // A tile: fp32 -> reg -> bf16 pack -> LDS (latency overlaps B's flight)
#pragma unroll
    for (int it = 0; it < 4; ++it) {
      int chunk = it * 256 + tid;
      int r = chunk >> 3, cc = (chunk & 7) * 8;
      const float* ap = &Ap[(size_t)(m0 + r) * K + k0 + cc];
      floatx4 f0 = *reinterpret_cast<const floatx4*>(ap);
      floatx4 f1 = *reinterpret_cast<const floatx4*>(ap + 4);
      uintx4 av;
      av[0] = pack_bf16(f0[0], f0[1]); av[1] = pack_bf16(f0[2], f0[3]);
      av[2] = pack_bf16(f1[0], f1[1]); av[3] = pack_bf16(f1[2], f1[3]);
      *reinterpret_cast<uintx4*>(&As[r * BK + cc]) = av;
    }
    __syncthreads();
#pragma unroll
    for (int kk = 0; kk < BK; kk += 32) {
      short8 af[4], bfr[4];
#pragma unroll
      for (int r = 0; r < 4; ++r)
        af[r] = *reinterpret_cast<const short8*>(
            &As[(wm + r * 16 + lm) * BK + kk + lq * 8]);
#pragma unroll
      for (int c = 0; c < 4; ++c)
        bfr[c] = *reinterpret_cast<const short8*>(
            &Bs[(wn + c * 16 + lm) * BK + kk + lq * 8]);
#pragma unroll
      for (int r = 0; r < 4; ++r)
#pragma unroll
        for (int c = 0; c < 4; ++c)
          acc[r][c] = __builtin_amdgcn_mfma_f32_16x16x32_bf16(
              af[r], bfr[c], acc[r][c], 0, 0, 0);
    }
  }

#pragma unroll
  for (int r = 0; r < 4; ++r)
#pragma unroll
    for (int c = 0; c < 4; ++c) {
      int col = n0 + wn + c * 16 + lm;
#pragma unroll
      for (int reg = 0; reg < 4; ++reg) {
        int row = m0 + wm + r * 16 + lq * 4 + reg;  // C/D: col=lane&15, row=quad*4+reg
        Cp[(size_t)row * N + col] = f2bs(acc[r][c][reg]);
      }
    }
}

// ---------------------------------------------------------------------------
// Out-projection GEMM: bf16 A via global_load_lds (m97 structure) + T1 swizzle.
// ---------------------------------------------------------------------------
template<int RESID, int OUTF32>
__global__ __launch_bounds__(256) void gemm_bt(
    const short* __restrict__ A, const short* __restrict__ BT,
    void* __restrict__ Cv, const short* __restrict__ resid,
    int M, int N, int K)
{
  __shared__ __align__(16) short As[BM * BK];
  __shared__ __align__(16) short Bs[BN * BK];
  const int tid  = threadIdx.x;
  const int wave = tid >> 6;
  const int lane = tid & 63;
  const int lm   = lane & 15;
  const int lq   = lane >> 4;
  int m0, n0;
  swizzle_mn(m0, n0);
  const int wm = (wave & 1) * 64;
  const int wn = (wave >> 1) * 64;

  floatx4 acc[4][4];
#pragma unroll
  for (int r = 0; r < 4; ++r)
#pragma unroll
    for (int c = 0; c < 4; ++c) acc[r][c] = (floatx4)0.0f;

  for (int k0 = 0; k0 < K; k0 += BK) {
    __syncthreads();
#pragma unroll
    for (int it = 0; it < 4; ++it) {
      int chunk = it * 256 + tid;
      int r = chunk >> 3, cc = (chunk & 7) * 8;
      async_copy16(&BT[(size_t)(n0 + r) * K + k0 + cc], &Bs[r * BK + cc]);
    }
#pragma unroll
    for (int it = 0; it < 4; ++it) {
      int chunk = it * 256 + tid;
      int r = chunk >> 3, cc = (chunk & 7) * 8;
      async_copy16(&A[(size_t)(m0 + r) * K + k0 + cc], &As[r * BK + cc]);
    }
    __syncthreads();
#pragma unroll
    for (int kk = 0; kk < BK; kk += 32) {
      short8 af[4], bfr[4];
#pragma unroll
      for (int r = 0; r < 4; ++r)
        af[r] = *reinterpret_cast<const short8*>(&As[(wm + r * 16 + lm) * BK + kk + lq * 8]);
#pragma unroll
      for (int c = 0; c < 4; ++c)
        bfr[c] = *reinterpret_cast<const short8*>(&Bs[(wn + c * 16 + lm) * BK + kk + lq * 8]);
#pragma unroll
      for (int r = 0; r < 4; ++r)
#pragma unroll
        for (int c = 0; c < 4; ++c)
          acc[r][c] = __builtin_amdgcn_mfma_f32_16x16x32_bf16(af[r], bfr[c], acc[r][c], 0, 0, 0);
    }
  }

#pragma unroll
  for (int r = 0; r < 4; ++r)
#pragma unroll
    for (int c = 0; c < 4; ++c) {
      int col = n0 + wn + c * 16 + lm;
#pragma unroll
      for (int reg = 0; reg < 4; ++reg) {
        int row = m0 + wm + r * 16 + lq * 4 + reg;   // C/D: col=lane&15, row=quad*4+reg
        size_t idx = (size_t)row * N + col;
        float v = acc[r][c][reg];
        if (RESID) v += bs2f(resid[idx]);
        if (OUTF32) ((float*)Cv)[idx] = v;
        else        ((short*)Cv)[idx] = f2bs(v);
      }
    }
}

// out[n][k] = bf16(in[k][n]) for 1024x1024 fp32; blockIdx.z selects matrix
__global__ __launch_bounds__(256) void transpose_cvt3(
    const float* __restrict__ i0, const float* __restrict__ i1,
    const float* __restrict__ i2, short* __restrict__ o0,
    short* __restrict__ o1, short* __restrict__ o2) {
  const float* in = blockIdx.z == 0 ? i0 : (blockIdx.z == 1 ? i1 : i2);
  short* out = blockIdx.z == 0 ? o0 : (blockIdx.z == 1 ? o1 : o2);
  __shared__ short tile[32][33];
  int bx = blockIdx.x * 32, by = blockIdx.y * 32;
  int tx = threadIdx.x & 31;
  int ty = threadIdx.x >> 5;
#pragma unroll
  for (int i = 0; i < 32; i += 8)
    tile[ty + i][tx] = f2bs(in[(size_t)(by + ty + i) * 1024 + bx + tx]);
  __syncthreads();
#pragma unroll
  for (int i = 0; i < 32; i += 8)
    out[(size_t)(bx + ty + i) * 1024 + by + tx] = tile[tx][ty + i];
}

// WaB[e][k] = bf16(Wa[k][e]), same for Wb. grid 128 x 256.
__global__ __launch_bounds__(256) void w_transpose(const float* __restrict__ Wa,
                                                   const float* __restrict__ Wb,
                                                   short* __restrict__ WaB,
                                                   short* __restrict__ WbB) {
  int idx = blockIdx.x * 256 + threadIdx.x;   // 0..32767
  const float* src = idx < 16384 ? Wa : Wb;
  short* dst = idx < 16384 ? WaB : WbB;
  int i = idx & 16383;
  int e = i >> 10, k = i & 1023;
  dst[i] = f2bs(src[k * 16 + e]);
}

// Skinny MFMA GEMM + fused exp: out[(b*16+e)*2048+s] = exp(0.125 * <A,W>).
// Max-subtraction-free softmax: glorot-scaled logits have std ~0.2-0.5, so
// fp32 exp cannot overflow; softmax(x) == exp(x)/sum(exp(x)) exactly.
// SCRAMBLE=0: A row = blk*16+m directly from X (Qb).
// SCRAMBLE=1: row sp=h*128+t reads X=Kb[b, t*16+u, h*64+j] * qg[b,h*64+j]
//             (the Fastformer reshape scramble; j-chunks stay contiguous).
// WB is W^T as bf16 [16][1024]. One wave per 16-row strip; grid 1024.
template<int SCRAMBLE>
__global__ __launch_bounds__(64) void skinny_logits(
    const short* __restrict__ X, const short* __restrict__ WB,
    const float* __restrict__ qg, float* __restrict__ out)
{
  const int lane = threadIdx.x;
  const int lm = lane & 15, lq = lane >> 4;
  const int blk = blockIdx.x;           // 0..1023
  const int b = blk >> 7;
  const int s0 = (blk & 127) * 16;      // row offset within batch
  floatx4 acc = (floatx4)0.0f;
  const short* b0 = WB + lm * 1024 + lq * 8;

  if (!SCRAMBLE) {
    const short* a0 = X + ((size_t)(b * 2048 + s0 + lm)) * 1024 + lq * 8;
#pragma unroll 16
    for (int c = 0; c < 32; ++c) {
      short8 a  = *reinterpret_cast<const short8*>(a0 + c * 32);
      short8 bf = *reinterpret_cast<const short8*>(b0 + c * 32);
      acc = __builtin_amdgcn_mfma_f32_16x16x32_bf16(a, bf, acc, 0, 0, 0);
    }
  } else {
    const int h = s0 >> 7, t0 = s0 & 127;
    const float* qgp = qg + b * 1024 + h * 64;
    const short* xb = X + ((size_t)(b * 2048 + (t0 + lm) * 16)) * 1024 + h * 64;
#pragma unroll 16
    for (int c = 0; c < 32; ++c) {
      int dp = c * 32 + lq * 8;         // k index within 1024
      int u = dp >> 6, j0 = dp & 63;    // 8-aligned, never crosses u
      short8 a = *reinterpret_cast<const short8*>(xb + (size_t)u * 1024 + j0);
      floatx4 g0 = *reinterpret_cast<const floatx4*>(qgp + j0);
      floatx4 g1 = *reinterpret_cast<const floatx4*>(qgp + j0 + 4);
      uintx4 av;
      av[0] = pack_bf16(bs2f(a[0]) * g0[0], bs2f(a[1]) * g0[1]);
      av[1] = pack_bf16(bs2f(a[2]) * g0[2], bs2f(a[3]) * g0[3]);
      av[2] = pack_bf16(bs2f(a[4]) * g1[0], bs2f(a[5]) * g1[1]);
      av[3] = pack_bf16(bs2f(a[6]) * g1[2], bs2f(a[7]) * g1[3]);
      short8 as = __builtin_bit_cast(short8, av);
      short8 bf = *reinterpret_cast<const short8*>(b0 + c * 32);
      acc = __builtin_amdgcn_mfma_f32_16x16x32_bf16(as, bf, acc, 0, 0, 0);
    }
  }
  // D: col(e)=lane&15, row=lq*4+reg; rows are consecutive s -> float4 store
  float* o = out + ((size_t)(b * 16 + lm)) * 2048 + s0 + lq * 4;
  floatx4 r;
#pragma unroll
  for (int i = 0; i < 4; ++i) r[i] = __expf(acc[i] * 0.125f);
  *reinterpret_cast<floatx4*>(o) = r;
}

// partial weighted pooling over UNNORMALIZED exp weights:
// grid 512 (b=blk>>6, sc=blk&63), 32 s-rows each.
// part[blk][d] = sum_{s in chunk} ew[b, d>>6, s] * X[b,s,d]
// psum[blk][h] = sum_{s in chunk} ew[b, h, s]   (for later normalization)
__global__ __launch_bounds__(256) void pool_partial(const float* __restrict__ ew,
                                                    const short* __restrict__ X,
                                                    float* __restrict__ part,
                                                    float* __restrict__ psum) {
  __shared__ float p[16][32];
  int blk = blockIdx.x, b = blk >> 6, sc = blk & 63, s0 = sc * 32;
  int tid = threadIdx.x;
  {
    int h = tid >> 4, ss = (tid & 15) * 2;
    const float* pr = ew + (size_t)(b * 16 + h) * 2048 + s0 + ss;
    p[h][ss] = pr[0]; p[h][ss + 1] = pr[1];
  }
  __syncthreads();
  if (tid < 16) {
    float s = 0.f;
#pragma unroll
    for (int j = 0; j < 32; ++j) s += p[tid][j];
    psum[blk * 16 + tid] = s;
  }
  int d = tid * 4, h = tid >> 4;
  float a0 = 0, a1 = 0, a2 = 0, a3 = 0;
  const short* Xp = X + ((size_t)b * 2048 + s0) * 1024 + d;
#pragma unroll 4
  for (int s = 0; s < 32; ++s) {
    sh4 x = *reinterpret_cast<const sh4*>(Xp + (size_t)s * 1024);
    float w = p[h][s];
    a0 += w * bs2f(x[0]); a1 += w * bs2f(x[1]);
    a2 += w * bs2f(x[2]); a3 += w * bs2f(x[3]);
  }
  float* o = part + (size_t)blk * 1024 + d;
  o[0] = a0; o[1] = a1; o[2] = a2; o[3] = a3;
}

// out[b*1024+d] = (SCALE ? g : 1) * (sum_sc part[..][d]) / (sum_sc psum[..][h])
// Normalization folded here -> softmax_rows kernels eliminated.
template<int SCALE>
__global__ __launch_bounds__(256) void pool_reduce(const float* __restrict__ part,
                                                   const float* __restrict__ psum,
                                                   const float* __restrict__ g,
                                                   float* __restrict__ out) {
  int b = blockIdx.x, d = threadIdx.x * 4, h = threadIdx.x >> 4;
  float a0 = 0, a1 = 0, a2 = 0, a3 = 0, hs = 0;
  for (int sc = 0; sc < 64; ++sc) {
    const float* pp = part + (size_t)(b * 64 + sc) * 1024 + d;
    a0 += pp[0]; a1 += pp[1]; a2 += pp[2]; a3 += pp[3];
    hs += psum[(b * 64 + sc) * 16 + h];   // same addr across 16 lanes: broadcast
  }
  float inv = 1.0f / hs;
  a0 *= inv; a1 *= inv; a2 *= inv; a3 *= inv;
  if (SCALE) {
    const float* gp = g + b * 1024 + d;
    a0 *= gp[0]; a1 *= gp[1]; a2 *= gp[2]; a3 *= gp[3];
  }
  float* op = out + b * 1024 + d;
  op[0] = a0; op[1] = a1; op[2] = a2; op[3] = a3;
}

// QG[b,s,d] = bf16( Qb[b,s,d] * g[b*1024+d] )
__global__ __launch_bounds__(256) void scale_a(const short* __restrict__ Qb,
                                               const float* __restrict__ g,
                                               short* __restrict__ QG) {
  size_t base = ((size_t)blockIdx.x * 256 + threadIdx.x) * 8;
  int b = (int)(base >> 21), d = (int)(base & 1023);
  short8 v = *reinterpret_cast<const short8*>(&Qb[base]);
  const float* gp = g + b * 1024 + d;
#pragma unroll
  for (int e = 0; e < 8; ++e) v[e] = f2bs(bs2f(v[e]) * gp[e]);
  *reinterpret_cast<short8*>(&QG[base]) = v;
}

extern "C" void kernel_launch(void* const* d_in, const int* in_sizes, int n_in,
                              void* d_out, int out_size, void* d_ws, size_t ws_size,
                              hipStream_t stream) {
  (void)in_sizes; (void)n_in; (void)out_size; (void)ws_size;
  const float* Qseq = (const float*)d_in[0];
  const float* Kseq = (const float*)d_in[1];
  // d_in[2] = V_seq, unused (faithful to reference)
  const float* WQ = (const float*)d_in[3];
  const float* WK = (const float*)d_in[4];
  const float* Wa = (const float*)d_in[5];
  const float* Wb = (const float*)d_in[6];
  const float* WP = (const float*)d_in[7];
  float* outp = (float*)d_out;

  char* ws = (char*)d_ws;
  const size_t MB = 1024 * 1024;
  short* Qb   = (short*)(ws + 0);           // 32 MB bf16 Q
  short* Kb   = (short*)(ws + 32 * MB);     // 32 MB bf16 K; reused for QG after pool2
  short* WQT  = (short*)(ws + 64 * MB);     // 2 MB
  short* WKT  = (short*)(ws + 66 * MB);     // 2 MB
  short* WPT  = (short*)(ws + 68 * MB);     // 2 MB
  float* la   = (float*)(ws + 70 * MB);     // 1 MB (exp of logits, chain 1)
  float* lb   = (float*)(ws + 71 * MB);     // 1 MB (exp of logits, chain 2)
  float* qg   = (float*)(ws + 72 * MB);     // 32 KB
  float* gv   = (float*)(ws + 72 * MB + 64 * 1024); // 32 KB
  short* WaB  = (short*)(ws + 72 * MB + 128 * 1024); // 32 KB bf16 Wa^T
  short* WbB  = (short*)(ws + 72 * MB + 192 * 1024); // 32 KB bf16 Wb^T
  float* part = (float*)(ws + 73 * MB);     // 2 MB
  float* psum = (float*)(ws + 75 * MB);     // 32 KB (512 x 16 exp partial sums)
  short* QG   = Kb;                         // Kb dead after pool2

  dim3 tb(256);
  transpose_cvt3<<<dim3(32, 32, 3), tb, 0, stream>>>(WQ, WK, WP, WQT, WKT, WPT);
  w_transpose<<<128, tb, 0, stream>>>(Wa, Wb, WaB, WbB);

  // fused Q/K projections (z selects problem), single-buffer + XCD swizzle
  gemm_proj<<<dim3(8, 128, 2), tb, 0, stream>>>(
      Qseq, WQT, Qb, Kseq, WKT, Kb, 1024, 1024);

  skinny_logits<0><<<1024, 64, 0, stream>>>(Qb, WaB, nullptr, la);
  pool_partial<<<512, tb, 0, stream>>>(la, Qb, part, psum);
  pool_reduce<0><<<8, tb, 0, stream>>>(part, psum, nullptr, qg);

  skinny_logits<1><<<1024, 64, 0, stream>>>(Kb, WbB, qg, lb);
  pool_partial<<<512, tb, 0, stream>>>(lb, Kb, part, psum);
  pool_reduce<1><<<8, tb, 0, stream>>>(part, psum, qg, gv);

  scale_a<<<8192, tb, 0, stream>>>(Qb, gv, QG);
  gemm_bt<1, 1><<<dim3(8, 128), tb, 0, stream>>>(QG, WPT, outp, Qb, 16384, 1024, 1024);
}

// Round 3
// 419.488 us; speedup vs baseline: 1.1628x; 1.0525x over previous
//
#include <hip/hip_runtime.h>
#include <stdint.h>

typedef __attribute__((ext_vector_type(8))) short short8;
typedef __attribute__((ext_vector_type(4))) short sh4;
typedef __attribute__((ext_vector_type(4))) float floatx4;
typedef __attribute__((ext_vector_type(4))) unsigned int uintx4;

__device__ __forceinline__ float bs2f(short s) {
  union { unsigned int u; float f; } cv;
  cv.u = ((unsigned int)(unsigned short)s) << 16;
  return cv.f;
}
__device__ __forceinline__ short f2bs(float x) {
  union { float f; unsigned int u; } cv; cv.f = x;
  unsigned int u = cv.u;
  u += 0x7fffu + ((u >> 16) & 1u);   // round-to-nearest-even
  return (short)(u >> 16);
}
// pack two fp32 -> bf16x2 (round-half-up) in 3 VALU: two adds + v_perm
__device__ __forceinline__ unsigned int pack_bf16(float a, float b) {
  unsigned int ua = __float_as_uint(a) + 0x8000u;
  unsigned int ub = __float_as_uint(b) + 0x8000u;
  return __builtin_amdgcn_perm(ub, ua, 0x07060302u);  // [ub.hi16 : ua.hi16]
}
// async global->LDS, 16 bytes per lane (wave-uniform LDS base + lane*16)
__device__ __forceinline__ void async_copy16(const void* g, void* l) {
  __builtin_amdgcn_global_load_lds(
      (const __attribute__((address_space(1))) void*)g,
      (__attribute__((address_space(3))) void*)l, 16, 0, 0);
}

// ---------------------------------------------------------------------------
// 256x256-tile GEMM geometry (m248-measured best structure at K=1024):
// BK=64, 8 waves (2M x 4N), per-wave output 128x64 (8x4 16x16 frags),
// 128 KB LDS double-buffer, minimum-2-phase pipeline:
//   loop: STAGE(buf^1) issued FIRST, compute(buf), A-pack write-late(buf^1),
//         ONE __syncthreads per K-step.
// K=1024 -> 16 K-steps. Grid per problem: 4 (n) x 64 (m) = 256 blocks.
// ---------------------------------------------------------------------------
#define PBM 256
#define PBN 256
#define PBK 64
#define PNT 16   // K / PBK

// T1 XCD swizzle for the 4x64 grid (256 blocks, %8==0 -> bijective):
// HW round-robins linear id over 8 XCDs; remap so XCD x owns m-strips
// [8x, 8x+8) with all 4 n-blocks -> A row-panels stay in one XCD's L2.
__device__ __forceinline__ void swizzle_mn256(int& m0, int& n0) {
  int flat = blockIdx.x + (blockIdx.y << 2);   // gridDim.x == 4
  int swz = (flat & 7) * 32 + (flat >> 3);     // chunk = 256/8 = 32
  n0 = (swz & 3) * PBN;
  m0 = (swz >> 2) * PBM;
}

// Fused Q/K projections: C = bf16( bf16(A_fp32) @ B^T ), blockIdx.z selects.
// A: fp32 reg-staged (issue-early) -> pack -> ds_write (write-late).
// B: bf16 via global_load_lds.
__global__ __launch_bounds__(512) void gemm_proj(
    const float* __restrict__ A0, const short* __restrict__ B0,
    short* __restrict__ C0,
    const float* __restrict__ A1, const short* __restrict__ B1,
    short* __restrict__ C1, int N, int K)
{
  __shared__ __align__(16) short As[2][PBM * PBK];   // 2 x 32 KB
  __shared__ __align__(16) short Bs[2][PBN * PBK];   // 2 x 32 KB
  const float* Ap = blockIdx.z ? A1 : A0;
  const short* Bp = blockIdx.z ? B1 : B0;
  short*       Cp = blockIdx.z ? C1 : C0;

  const int tid = threadIdx.x;
  const int wave = tid >> 6, lane = tid & 63;
  const int lm = lane & 15, lq = lane >> 4;
  const int wr = wave >> 2, wc = wave & 3;    // 2M x 4N wave grid
  int m0, n0;
  swizzle_mn256(m0, n0);
  const int r8 = tid >> 3, cc = (tid & 7) * 8;   // staging coords

  floatx4 acc[8][4];
#pragma unroll
  for (int r = 0; r < 8; ++r)
#pragma unroll
    for (int c = 0; c < 4; ++c) acc[r][c] = (floatx4)0.0f;

  floatx4 pa[4][2];   // in-flight fp32 A (static indexing only)

  auto stageB = [&](int buf, int kb) {
#pragma unroll
    for (int it = 0; it < 4; ++it) {
      int r = it * 64 + r8;
      async_copy16(&Bp[(size_t)(n0 + r) * K + kb + cc], &Bs[buf][r * PBK + cc]);
    }
  };
  auto loadA = [&](int kb) {
#pragma unroll
    for (int it = 0; it < 4; ++it) {
      const float* ap = Ap + (size_t)(m0 + it * 64 + r8) * K + kb + cc;
      pa[it][0] = *reinterpret_cast<const floatx4*>(ap);
      pa[it][1] = *reinterpret_cast<const floatx4*>(ap + 4);
    }
  };
  auto packA = [&](int buf) {
#pragma unroll
    for (int it = 0; it < 4; ++it) {
      uintx4 av;
      av[0] = pack_bf16(pa[it][0][0], pa[it][0][1]);
      av[1] = pack_bf16(pa[it][0][2], pa[it][0][3]);
      av[2] = pack_bf16(pa[it][1][0], pa[it][1][1]);
      av[3] = pack_bf16(pa[it][1][2], pa[it][1][3]);
      *reinterpret_cast<uintx4*>(&As[buf][(it * 64 + r8) * PBK + cc]) = av;
    }
  };
  auto compute = [&](int buf) {
#pragma unroll
    for (int kk = 0; kk < PBK; kk += 32) {
      short8 af[8], bfr[4];
#pragma unroll
      for (int r = 0; r < 8; ++r)
        af[r] = *reinterpret_cast<const short8*>(
            &As[buf][(wr * 128 + r * 16 + lm) * PBK + kk + lq * 8]);
#pragma unroll
      for (int c = 0; c < 4; ++c)
        bfr[c] = *reinterpret_cast<const short8*>(
            &Bs[buf][(wc * 64 + c * 16 + lm) * PBK + kk + lq * 8]);
#pragma unroll
      for (int r = 0; r < 8; ++r)
#pragma unroll
        for (int c = 0; c < 4; ++c)
          acc[r][c] = __builtin_amdgcn_mfma_f32_16x16x32_bf16(
              af[r], bfr[c], acc[r][c], 0, 0, 0);
    }
  };

  // prologue: tile 0 into buffer 0
  stageB(0, 0);
  loadA(0);
  packA(0);
  __syncthreads();

  int cur = 0;
  for (int t = 0; t < PNT - 1; ++t) {
    const int nxt = cur ^ 1;
    const int kb = (t + 1) * PBK;
    stageB(nxt, kb);       // issue-early: async B loads fly under compute
    loadA(kb);             // issue-early: fp32 A loads fly under compute
    compute(cur);
    packA(nxt);            // write-late: loads had the whole MFMA phase
    __syncthreads();       // single barrier per K-step (drains vm+lgkm)
    cur = nxt;
  }
  compute(cur);

#pragma unroll
  for (int r = 0; r < 8; ++r)
#pragma unroll
    for (int c = 0; c < 4; ++c) {
      int col = n0 + wc * 64 + c * 16 + lm;
#pragma unroll
      for (int reg = 0; reg < 4; ++reg) {
        int row = m0 + wr * 128 + r * 16 + lq * 4 + reg;  // C/D: col=lane&15
        Cp[(size_t)row * N + col] = f2bs(acc[r][c][reg]);
      }
    }
}

// Out-projection, same 256x256 2-phase structure, with scale_a FOLDED into
// A-staging: A = bf16( Qb[row,k] * gv[b,k] ) computed in fp32 during pack.
// Epilogue: fp32 out + bf16 residual (Qb).
__global__ __launch_bounds__(512) void gemm_out(
    const short* __restrict__ Aq, const float* __restrict__ gvp,
    const short* __restrict__ BT, float* __restrict__ Cv,
    const short* __restrict__ resid, int N, int K)
{
  __shared__ __align__(16) short As[2][PBM * PBK];
  __shared__ __align__(16) short Bs[2][PBN * PBK];

  const int tid = threadIdx.x;
  const int wave = tid >> 6, lane = tid & 63;
  const int lm = lane & 15, lq = lane >> 4;
  const int wr = wave >> 2, wc = wave & 3;
  int m0, n0;
  swizzle_mn256(m0, n0);
  const int r8 = tid >> 3, cc = (tid & 7) * 8;
  const int bq = m0 >> 11;          // batch (256-row tile never crosses 2048)

  floatx4 acc[8][4];
#pragma unroll
  for (int r = 0; r < 8; ++r)
#pragma unroll
    for (int c = 0; c < 4; ++c) acc[r][c] = (floatx4)0.0f;

  short8 qa[4];        // in-flight bf16 A rows
  floatx4 g0, g1;      // gv slice (same k-slice for all 4 its)

  auto stageB = [&](int buf, int kb) {
#pragma unroll
    for (int it = 0; it < 4; ++it) {
      int r = it * 64 + r8;
      async_copy16(&BT[(size_t)(n0 + r) * K + kb + cc], &Bs[buf][r * PBK + cc]);
    }
  };
  auto loadA = [&](int kb) {
#pragma unroll
    for (int it = 0; it < 4; ++it)
      qa[it] = *reinterpret_cast<const short8*>(
          &Aq[(size_t)(m0 + it * 64 + r8) * K + kb + cc]);
    g0 = *reinterpret_cast<const floatx4*>(gvp + bq * 1024 + kb + cc);
    g1 = *reinterpret_cast<const floatx4*>(gvp + bq * 1024 + kb + cc + 4);
  };
  auto packA = [&](int buf) {
#pragma unroll
    for (int it = 0; it < 4; ++it) {
      uintx4 av;
      av[0] = pack_bf16(bs2f(qa[it][0]) * g0[0], bs2f(qa[it][1]) * g0[1]);
      av[1] = pack_bf16(bs2f(qa[it][2]) * g0[2], bs2f(qa[it][3]) * g0[3]);
      av[2] = pack_bf16(bs2f(qa[it][4]) * g1[0], bs2f(qa[it][5]) * g1[1]);
      av[3] = pack_bf16(bs2f(qa[it][6]) * g1[2], bs2f(qa[it][7]) * g1[3]);
      *reinterpret_cast<uintx4*>(&As[buf][(it * 64 + r8) * PBK + cc]) = av;
    }
  };
  auto compute = [&](int buf) {
#pragma unroll
    for (int kk = 0; kk < PBK; kk += 32) {
      short8 af[8], bfr[4];
#pragma unroll
      for (int r = 0; r < 8; ++r)
        af[r] = *reinterpret_cast<const short8*>(
            &As[buf][(wr * 128 + r * 16 + lm) * PBK + kk + lq * 8]);
#pragma unroll
      for (int c = 0; c < 4; ++c)
        bfr[c] = *reinterpret_cast<const short8*>(
            &Bs[buf][(wc * 64 + c * 16 + lm) * PBK + kk + lq * 8]);
#pragma unroll
      for (int r = 0; r < 8; ++r)
#pragma unroll
        for (int c = 0; c < 4; ++c)
          acc[r][c] = __builtin_amdgcn_mfma_f32_16x16x32_bf16(
              af[r], bfr[c], acc[r][c], 0, 0, 0);
    }
  };

  stageB(0, 0);
  loadA(0);
  packA(0);
  __syncthreads();

  int cur = 0;
  for (int t = 0; t < PNT - 1; ++t) {
    const int nxt = cur ^ 1;
    const int kb = (t + 1) * PBK;
    stageB(nxt, kb);
    loadA(kb);
    compute(cur);
    packA(nxt);
    __syncthreads();
    cur = nxt;
  }
  compute(cur);

#pragma unroll
  for (int r = 0; r < 8; ++r)
#pragma unroll
    for (int c = 0; c < 4; ++c) {
      int col = n0 + wc * 64 + c * 16 + lm;
#pragma unroll
      for (int reg = 0; reg < 4; ++reg) {
        int row = m0 + wr * 128 + r * 16 + lq * 4 + reg;
        size_t idx = (size_t)row * N + col;
        Cv[idx] = acc[r][c][reg] + bs2f(resid[idx]);
      }
    }
}

// out[n][k] = bf16(in[k][n]) for 1024x1024 fp32; blockIdx.z selects matrix
__global__ __launch_bounds__(256) void transpose_cvt3(
    const float* __restrict__ i0, const float* __restrict__ i1,
    const float* __restrict__ i2, short* __restrict__ o0,
    short* __restrict__ o1, short* __restrict__ o2) {
  const float* in = blockIdx.z == 0 ? i0 : (blockIdx.z == 1 ? i1 : i2);
  short* out = blockIdx.z == 0 ? o0 : (blockIdx.z == 1 ? o1 : o2);
  __shared__ short tile[32][33];
  int bx = blockIdx.x * 32, by = blockIdx.y * 32;
  int tx = threadIdx.x & 31;
  int ty = threadIdx.x >> 5;
#pragma unroll
  for (int i = 0; i < 32; i += 8)
    tile[ty + i][tx] = f2bs(in[(size_t)(by + ty + i) * 1024 + bx + tx]);
  __syncthreads();
#pragma unroll
  for (int i = 0; i < 32; i += 8)
    out[(size_t)(bx + ty + i) * 1024 + by + tx] = tile[tx][ty + i];
}

// WaB[e][k] = bf16(Wa[k][e]), same for Wb. grid 128 x 256.
__global__ __launch_bounds__(256) void w_transpose(const float* __restrict__ Wa,
                                                   const float* __restrict__ Wb,
                                                   short* __restrict__ WaB,
                                                   short* __restrict__ WbB) {
  int idx = blockIdx.x * 256 + threadIdx.x;   // 0..32767
  const float* src = idx < 16384 ? Wa : Wb;
  short* dst = idx < 16384 ? WaB : WbB;
  int i = idx & 16383;
  int e = i >> 10, k = i & 1023;
  dst[i] = f2bs(src[k * 16 + e]);
}

// Skinny MFMA GEMM + fused exp: out[(b*16+e)*2048+s] = exp(0.125 * <A,W>).
// Max-subtraction-free softmax: glorot-scaled logits are O(1), fp32 exp safe.
template<int SCRAMBLE>
__global__ __launch_bounds__(64) void skinny_logits(
    const short* __restrict__ X, const short* __restrict__ WB,
    const float* __restrict__ qg, float* __restrict__ out)
{
  const int lane = threadIdx.x;
  const int lm = lane & 15, lq = lane >> 4;
  const int blk = blockIdx.x;           // 0..1023
  const int b = blk >> 7;
  const int s0 = (blk & 127) * 16;      // row offset within batch
  floatx4 acc = (floatx4)0.0f;
  const short* b0 = WB + lm * 1024 + lq * 8;

  if (!SCRAMBLE) {
    const short* a0 = X + ((size_t)(b * 2048 + s0 + lm)) * 1024 + lq * 8;
#pragma unroll 16
    for (int c = 0; c < 32; ++c) {
      short8 a  = *reinterpret_cast<const short8*>(a0 + c * 32);
      short8 bf = *reinterpret_cast<const short8*>(b0 + c * 32);
      acc = __builtin_amdgcn_mfma_f32_16x16x32_bf16(a, bf, acc, 0, 0, 0);
    }
  } else {
    const int h = s0 >> 7, t0 = s0 & 127;
    const float* qgp = qg + b * 1024 + h * 64;
    const short* xb = X + ((size_t)(b * 2048 + (t0 + lm) * 16)) * 1024 + h * 64;
#pragma unroll 16
    for (int c = 0; c < 32; ++c) {
      int dp = c * 32 + lq * 8;         // k index within 1024
      int u = dp >> 6, j0 = dp & 63;    // 8-aligned, never crosses u
      short8 a = *reinterpret_cast<const short8*>(xb + (size_t)u * 1024 + j0);
      floatx4 g0 = *reinterpret_cast<const floatx4*>(qgp + j0);
      floatx4 g1 = *reinterpret_cast<const floatx4*>(qgp + j0 + 4);
      uintx4 av;
      av[0] = pack_bf16(bs2f(a[0]) * g0[0], bs2f(a[1]) * g0[1]);
      av[1] = pack_bf16(bs2f(a[2]) * g0[2], bs2f(a[3]) * g0[3]);
      av[2] = pack_bf16(bs2f(a[4]) * g1[0], bs2f(a[5]) * g1[1]);
      av[3] = pack_bf16(bs2f(a[6]) * g1[2], bs2f(a[7]) * g1[3]);
      short8 as = __builtin_bit_cast(short8, av);
      short8 bf = *reinterpret_cast<const short8*>(b0 + c * 32);
      acc = __builtin_amdgcn_mfma_f32_16x16x32_bf16(as, bf, acc, 0, 0, 0);
    }
  }
  // D: col(e)=lane&15, row=lq*4+reg; rows are consecutive s -> float4 store
  float* o = out + ((size_t)(b * 16 + lm)) * 2048 + s0 + lq * 4;
  floatx4 r;
#pragma unroll
  for (int i = 0; i < 4; ++i) r[i] = __expf(acc[i] * 0.125f);
  *reinterpret_cast<floatx4*>(o) = r;
}

// partial weighted pooling over UNNORMALIZED exp weights:
// grid 512 (b=blk>>6, sc=blk&63), 32 s-rows each.
// part[blk][d] = sum_{s in chunk} ew[b, d>>6, s] * X[b,s,d]
// psum[blk][h] = sum_{s in chunk} ew[b, h, s]
__global__ __launch_bounds__(256) void pool_partial(const float* __restrict__ ew,
                                                    const short* __restrict__ X,
                                                    float* __restrict__ part,
                                                    float* __restrict__ psum) {
  __shared__ float p[16][32];
  int blk = blockIdx.x, b = blk >> 6, sc = blk & 63, s0 = sc * 32;
  int tid = threadIdx.x;
  {
    int h = tid >> 4, ss = (tid & 15) * 2;
    const float* pr = ew + (size_t)(b * 16 + h) * 2048 + s0 + ss;
    p[h][ss] = pr[0]; p[h][ss + 1] = pr[1];
  }
  __syncthreads();
  if (tid < 16) {
    float s = 0.f;
#pragma unroll
    for (int j = 0; j < 32; ++j) s += p[tid][j];
    psum[blk * 16 + tid] = s;
  }
  int d = tid * 4, h = tid >> 4;
  float a0 = 0, a1 = 0, a2 = 0, a3 = 0;
  const short* Xp = X + ((size_t)b * 2048 + s0) * 1024 + d;
#pragma unroll 4
  for (int s = 0; s < 32; ++s) {
    sh4 x = *reinterpret_cast<const sh4*>(Xp + (size_t)s * 1024);
    float w = p[h][s];
    a0 += w * bs2f(x[0]); a1 += w * bs2f(x[1]);
    a2 += w * bs2f(x[2]); a3 += w * bs2f(x[3]);
  }
  float* o = part + (size_t)blk * 1024 + d;
  o[0] = a0; o[1] = a1; o[2] = a2; o[3] = a3;
}

// out[b*1024+d] = (SCALE ? g : 1) * (sum_sc part[..][d]) / (sum_sc psum[..][h])
template<int SCALE>
__global__ __launch_bounds__(256) void pool_reduce(const float* __restrict__ part,
                                                   const float* __restrict__ psum,
                                                   const float* __restrict__ g,
                                                   float* __restrict__ out) {
  int b = blockIdx.x, d = threadIdx.x * 4, h = threadIdx.x >> 4;
  float a0 = 0, a1 = 0, a2 = 0, a3 = 0, hs = 0;
  for (int sc = 0; sc < 64; ++sc) {
    const float* pp = part + (size_t)(b * 64 + sc) * 1024 + d;
    a0 += pp[0]; a1 += pp[1]; a2 += pp[2]; a3 += pp[3];
    hs += psum[(b * 64 + sc) * 16 + h];   // same addr across 16 lanes: broadcast
  }
  float inv = 1.0f / hs;
  a0 *= inv; a1 *= inv; a2 *= inv; a3 *= inv;
  if (SCALE) {
    const float* gp = g + b * 1024 + d;
    a0 *= gp[0]; a1 *= gp[1]; a2 *= gp[2]; a3 *= gp[3];
  }
  float* op = out + b * 1024 + d;
  op[0] = a0; op[1] = a1; op[2] = a2; op[3] = a3;
}

extern "C" void kernel_launch(void* const* d_in, const int* in_sizes, int n_in,
                              void* d_out, int out_size, void* d_ws, size_t ws_size,
                              hipStream_t stream) {
  (void)in_sizes; (void)n_in; (void)out_size; (void)ws_size;
  const float* Qseq = (const float*)d_in[0];
  const float* Kseq = (const float*)d_in[1];
  // d_in[2] = V_seq, unused (faithful to reference)
  const float* WQ = (const float*)d_in[3];
  const float* WK = (const float*)d_in[4];
  const float* Wa = (const float*)d_in[5];
  const float* Wb = (const float*)d_in[6];
  const float* WP = (const float*)d_in[7];
  float* outp = (float*)d_out;

  char* ws = (char*)d_ws;
  const size_t MB = 1024 * 1024;
  short* Qb   = (short*)(ws + 0);           // 32 MB bf16 Q
  short* Kb   = (short*)(ws + 32 * MB);     // 32 MB bf16 K
  short* WQT  = (short*)(ws + 64 * MB);     // 2 MB
  short* WKT  = (short*)(ws + 66 * MB);     // 2 MB
  short* WPT  = (short*)(ws + 68 * MB);     // 2 MB
  float* la   = (float*)(ws + 70 * MB);     // 1 MB (exp of logits, chain 1)
  float* lb   = (float*)(ws + 71 * MB);     // 1 MB (exp of logits, chain 2)
  float* qg   = (float*)(ws + 72 * MB);     // 32 KB
  float* gv   = (float*)(ws + 72 * MB + 64 * 1024); // 32 KB
  short* WaB  = (short*)(ws + 72 * MB + 128 * 1024); // 32 KB bf16 Wa^T
  short* WbB  = (short*)(ws + 72 * MB + 192 * 1024); // 32 KB bf16 Wb^T
  float* part = (float*)(ws + 73 * MB);     // 2 MB
  float* psum = (float*)(ws + 75 * MB);     // 32 KB

  dim3 tb(256);
  transpose_cvt3<<<dim3(32, 32, 3), tb, 0, stream>>>(WQ, WK, WP, WQT, WKT, WPT);
  w_transpose<<<128, tb, 0, stream>>>(Wa, Wb, WaB, WbB);

  // fused Q/K projections: 256^2 tile, 2-phase dbuf, XCD swizzle
  gemm_proj<<<dim3(4, 64, 2), dim3(512), 0, stream>>>(
      Qseq, WQT, Qb, Kseq, WKT, Kb, 1024, 1024);

  skinny_logits<0><<<1024, 64, 0, stream>>>(Qb, WaB, nullptr, la);
  pool_partial<<<512, tb, 0, stream>>>(la, Qb, part, psum);
  pool_reduce<0><<<8, tb, 0, stream>>>(part, psum, nullptr, qg);

  skinny_logits<1><<<1024, 64, 0, stream>>>(Kb, WbB, qg, lb);
  pool_partial<<<512, tb, 0, stream>>>(lb, Kb, part, psum);
  pool_reduce<1><<<8, tb, 0, stream>>>(part, psum, qg, gv);

  // out-projection with scale_a folded into A-staging (QG never materialized)
  gemm_out<<<dim3(4, 64), dim3(512), 0, stream>>>(
      Qb, gv, WPT, outp, Qb, 1024, 1024);
}